// Round 1
// baseline (314.923 us; speedup 1.0000x reference)
//
#include <hip/hip_runtime.h>
#include <math.h>

#define N_INP 128
#define N_HID 512
#define N_OUT 256
#define N_HEADS 64
#define N_SM 4
#define EPS_GN 1e-5f
#define TINY 1e-14f

__device__ __forceinline__ float wave_sum(float v) {
#pragma unroll
  for (int off = 32; off; off >>= 1) v += __shfl_down(v, off);
  return v;
}
__device__ __forceinline__ float wave_max(float v) {
#pragma unroll
  for (int off = 32; off; off >>= 1) v = fmaxf(v, __shfl_down(v, off));
  return v;
}

// Block reductions: all threads must call; `red` needs blockDim/64 slots.
__device__ __forceinline__ float block_sum(float v, float* red) {
  int wave = threadIdx.x >> 6, lane = threadIdx.x & 63;
  int nw = blockDim.x >> 6;
  v = wave_sum(v);
  __syncthreads();
  if (lane == 0) red[wave] = v;
  __syncthreads();
  float s = 0.f;
  for (int i = 0; i < nw; ++i) s += red[i];
  return s;
}
__device__ __forceinline__ float block_max(float v, float* red) {
  int wave = threadIdx.x >> 6, lane = threadIdx.x & 63;
  int nw = blockDim.x >> 6;
  v = wave_max(v);
  __syncthreads();
  if (lane == 0) red[wave] = v;
  __syncthreads();
  float s = -3.4e38f;
  for (int i = 0; i < nw; ++i) s = fmaxf(s, red[i]);
  return s;
}

// Kernel 1: sub[h][r] = sum_c x[r][c]*qw[h][c]  (recomputed per block, tiny)
// then z1[h][o] = sum_i w1[h][o][i]*sub[h][i] for this block's 128 o's.
// Also zeroes the out_sm accumulator.
__global__ __launch_bounds__(256) void k_sub_z1(
    const float* __restrict__ x, const float* __restrict__ qw,
    const float* __restrict__ w1, float* __restrict__ z1,
    float* __restrict__ osm) {
  int blk = blockIdx.x;            // h*4 + oq
  int h = blk >> 2, oq = blk & 3;
  int tid = threadIdx.x;
  int wave = tid >> 6, lane = tid & 63;

  int gi = blk * 256 + tid;
  if (gi < N_OUT * N_HEADS) osm[gi] = 0.f;

  __shared__ float sub_s[N_INP];
  const float2* qv2 = (const float2*)(qw + h * N_INP);
  float2 qv = qv2[lane];           // qw[h][2l..2l+1]
  for (int r = wave; r < N_INP; r += 4) {
    float2 xv = ((const float2*)(x + r * N_INP))[lane];
    float p = xv.x * qv.x + xv.y * qv.y;
    p = wave_sum(p);
    if (lane == 0) sub_s[r] = p;
  }
  __syncthreads();
  float2 sv = ((const float2*)sub_s)[lane];   // sub[2l..2l+1]
  for (int k = 0; k < 32; ++k) {
    int o = oq * 128 + wave * 32 + k;
    const float2 wv = ((const float2*)(w1 + (size_t)(h * N_HID + o) * N_INP))[lane];
    float p = wv.x * sv.x + wv.y * sv.y;
    p = wave_sum(p);
    if (lane == 0) z1[h * N_HID + o] = p;
  }
}

// Kernel 2: GroupNorm over 512 per head + softplus -> h1
__global__ __launch_bounds__(512) void k_gn1(
    const float* __restrict__ z1, const float* __restrict__ g,
    const float* __restrict__ b, float* __restrict__ h1) {
  __shared__ float red[8];
  int h = blockIdx.x, t = threadIdx.x;
  float v = z1[h * N_HID + t];
  float s = block_sum(v, red);
  float ss = block_sum(v * v, red);
  float mu = s * (1.f / N_HID);
  float var = ss * (1.f / N_HID) - mu * mu;
  float r = rsqrtf(var + EPS_GN);
  float zz = (v - mu) * r * g[h * N_HID + t] + b[h * N_HID + t];
  // stable softplus = max(z,0) + log1p(exp(-|z|))
  float sp = fmaxf(zz, 0.f) + log1pf(expf(-fabsf(zz)));
  h1[h * N_HID + t] = sp;
}

// Kernel 3: scalar[o][h] = sum_i ws[h][o][i]
__global__ __launch_bounds__(256) void k_scalar(
    const float* __restrict__ wsc, float* __restrict__ scal) {
  int blk = blockIdx.x;            // h*4 + oq
  int h = blk >> 2, oq = blk & 3;
  int wave = threadIdx.x >> 6, lane = threadIdx.x & 63;
  for (int k = 0; k < 16; ++k) {
    int o = oq * 64 + wave * 16 + k;
    float4 v = ((const float4*)(wsc + ((size_t)(h * N_OUT + o)) * N_OUT))[lane];
    float p = v.x + v.y + v.z + v.w;
    p = wave_sum(p);
    if (lane == 0) scal[o * N_HEADS + h] = p;
  }
}

// Kernel 4 (the big stream): z[s][h][o] = w2[s][h][o][:].h1[h][:],
// GroupNorm(256) + softmax(256), atomicAdd into out_sm[o][h].
__global__ __launch_bounds__(1024) void k_l2(
    const float* __restrict__ w2, const float* __restrict__ h1,
    const float* __restrict__ g2, const float* __restrict__ b2,
    float* __restrict__ osm) {
  int blk = blockIdx.x;            // s*64 + h
  int h = blk & 63;
  int tid = threadIdx.x;
  int wave = tid >> 6, lane = tid & 63;
  __shared__ float z_s[N_OUT];
  __shared__ float red[16];

  // per-lane o-invariant h1 fragment in registers
  const float4* h1v = (const float4*)(h1 + h * N_HID);
  float4 ha = h1v[lane];        // i = 4l..4l+3
  float4 hb = h1v[64 + lane];   // i = 256+4l..
  const float* w2base = w2 + (size_t)blk * N_OUT * N_HID;
  for (int k = 0; k < 16; ++k) {
    int o = wave * 16 + k;
    const float4* row = (const float4*)(w2base + (size_t)o * N_HID);
    float4 wa = row[lane];
    float4 wb = row[64 + lane];
    float p = wa.x * ha.x + wa.y * ha.y + wa.z * ha.z + wa.w * ha.w +
              wb.x * hb.x + wb.y * hb.y + wb.z * hb.z + wb.w * hb.w;
    p = wave_sum(p);
    if (lane == 0) z_s[o] = p;
  }
  __syncthreads();

  float v = (tid < N_OUT) ? z_s[tid] : 0.f;
  float s = block_sum(v, red);
  float ss = block_sum(v * v, red);
  float mu = s * (1.f / N_OUT);
  float var = ss * (1.f / N_OUT) - mu * mu;
  float rs = rsqrtf(var + EPS_GN);
  float zn = (tid < N_OUT)
                 ? (v - mu) * rs * g2[(size_t)blk * N_OUT + tid] + b2[(size_t)blk * N_OUT + tid]
                 : -3.4e38f;
  float mx = block_max(zn, red);
  float e = (tid < N_OUT) ? expf(zn - mx) : 0.f;
  float es = block_sum(e, red);
  if (tid < N_OUT) atomicAdd(&osm[tid * N_HEADS + h], e / es);
}

// Kernel 5: gate logits + sigmoid (tiny; 1 block)
__global__ __launch_bounds__(256) void k_gate(
    const float* __restrict__ last, const float* __restrict__ woo,
    const float* __restrict__ osm, float* __restrict__ onoff) {
  __shared__ float lp[N_OUT];
  int tid = threadIdx.x;
  float p = 1.f;
  const float* row = last + (size_t)tid * N_HEADS;
  for (int h = 0; h < N_HEADS; ++h) p *= row[h];
  lp[tid] = p;
  __syncthreads();
  int wave = tid >> 6, lane = tid & 63;
  for (int h = wave; h < N_HEADS; h += 4) {
    float acc = 0.f;
#pragma unroll
    for (int j = 0; j < 4; ++j) {
      int o = lane * 4 + j;
      acc += woo[h * 2 * N_OUT + o] * lp[o] +
             woo[h * 2 * N_OUT + N_OUT + o] * osm[o * N_HEADS + h];
    }
    acc = wave_sum(acc);
    if (lane == 0) onoff[h] = 1.f / (1.f + expf(-acc));
  }
}

// Kernel 6: final elementwise outputs
__global__ __launch_bounds__(256) void k_final(
    const float* __restrict__ osm, const float* __restrict__ scal,
    const float* __restrict__ onoff, float* __restrict__ out) {
  int i = blockIdx.x * 256 + threadIdx.x;  // 0..16383
  int h = i & 63;
  float oo = onoff[h];
  float v0 = oo * osm[i];
  out[i] = fmaxf(v0, TINY);
  float v1 = v0 * scal[i];
  out[N_OUT * N_HEADS + i] = (fabsf(v1) <= TINY) ? TINY : v1;
}

extern "C" void kernel_launch(void* const* d_in, const int* in_sizes, int n_in,
                              void* d_out, int out_size, void* d_ws, size_t ws_size,
                              hipStream_t stream) {
  const float* x    = (const float*)d_in[0];
  const float* last = (const float*)d_in[1];
  const float* qw   = (const float*)d_in[2];
  const float* w1   = (const float*)d_in[3];
  const float* g1   = (const float*)d_in[4];
  const float* b1   = (const float*)d_in[5];
  const float* w2   = (const float*)d_in[6];
  const float* g2   = (const float*)d_in[7];
  const float* b2   = (const float*)d_in[8];
  const float* wsc  = (const float*)d_in[9];
  const float* woo  = (const float*)d_in[10];
  float* out = (float*)d_out;
  float* ws  = (float*)d_ws;

  float* z1    = ws;            // 64*512
  float* h1    = ws + 32768;    // 64*512
  float* osm   = ws + 65536;    // 256*64
  float* scal  = ws + 81920;    // 256*64
  float* onoff = ws + 98304;    // 64

  hipLaunchKernelGGL(k_sub_z1, dim3(256), dim3(256), 0, stream, x, qw, w1, z1, osm);
  hipLaunchKernelGGL(k_gn1,    dim3(64),  dim3(512), 0, stream, z1, g1, b1, h1);
  hipLaunchKernelGGL(k_scalar, dim3(256), dim3(256), 0, stream, wsc, scal);
  hipLaunchKernelGGL(k_l2,     dim3(256), dim3(1024), 0, stream, w2, h1, g2, b2, osm);
  hipLaunchKernelGGL(k_gate,   dim3(1),   dim3(256), 0, stream, last, woo, osm, onoff);
  hipLaunchKernelGGL(k_final,  dim3(64),  dim3(256), 0, stream, osm, scal, onoff, out);
}

// Round 2
// 294.707 us; speedup vs baseline: 1.0686x; 1.0686x over previous
//
#include <hip/hip_runtime.h>
#include <math.h>

#define N_INP 128
#define N_HID 512
#define N_OUT 256
#define N_HEADS 64
#define N_SM 4
#define EPS_GN 1e-5f
#define TINY 1e-14f

__device__ __forceinline__ float wave_sum(float v) {
#pragma unroll
  for (int off = 32; off; off >>= 1) v += __shfl_down(v, off);
  return v;
}
__device__ __forceinline__ float wave_max(float v) {
#pragma unroll
  for (int off = 32; off; off >>= 1) v = fmaxf(v, __shfl_down(v, off));
  return v;
}

// Block reductions: ALL threads must call; `red` needs blockDim/64 slots.
__device__ __forceinline__ float block_sum(float v, float* red) {
  int wave = threadIdx.x >> 6, lane = threadIdx.x & 63;
  int nw = blockDim.x >> 6;
  v = wave_sum(v);
  __syncthreads();
  if (lane == 0) red[wave] = v;
  __syncthreads();
  float s = 0.f;
  for (int i = 0; i < nw; ++i) s += red[i];
  return s;
}
__device__ __forceinline__ float block_max(float v, float* red) {
  int wave = threadIdx.x >> 6, lane = threadIdx.x & 63;
  int nw = blockDim.x >> 6;
  v = wave_max(v);
  __syncthreads();
  if (lane == 0) red[wave] = v;
  __syncthreads();
  float s = -3.4e38f;
  for (int i = 0; i < nw; ++i) s = fmaxf(s, red[i]);
  return s;
}

// K1: one block per head. sub -> z1 (LDS) -> GroupNorm -> softplus -> h1.
// Also zero-inits the out_sm accumulator slice.
__global__ __launch_bounds__(512) void k_head1(
    const float* __restrict__ x, const float* __restrict__ qw,
    const float* __restrict__ w1, const float* __restrict__ g1,
    const float* __restrict__ b1, float* __restrict__ h1,
    float* __restrict__ osm) {
  int h = blockIdx.x;
  int tid = threadIdx.x, wave = tid >> 6, lane = tid & 63;
  __shared__ float sub_s[N_INP];
  __shared__ float z_s[N_HID];
  __shared__ float red[8];

  if (tid < 256) osm[h * 256 + tid] = 0.f;  // arbitrary 256-elem slice of the 16384

  // sub[r] = x[r]·qw[h]; 8 waves × 16 rows
  float2 qv = ((const float2*)(qw + h * N_INP))[lane];
  for (int r = wave; r < N_INP; r += 8) {
    float2 xv = ((const float2*)(x + r * N_INP))[lane];
    float p = wave_sum(xv.x * qv.x + xv.y * qv.y);
    if (lane == 0) sub_s[r] = p;
  }
  __syncthreads();

  // z1[o] = w1[h][o]·sub; 8 waves × 64 rows, wave-coalesced float2 per lane
  float2 sv = ((const float2*)sub_s)[lane];
  const float* w1h = w1 + (size_t)h * N_HID * N_INP;
  for (int k = 0; k < 64; ++k) {
    int o = wave * 64 + k;
    float2 wv = ((const float2*)(w1h + (size_t)o * N_INP))[lane];
    float p = wave_sum(wv.x * sv.x + wv.y * sv.y);
    if (lane == 0) z_s[o] = p;
  }
  __syncthreads();

  // GroupNorm over 512 + softplus
  float v = z_s[tid];
  float s = block_sum(v, red);
  float ss = block_sum(v * v, red);
  float mu = s * (1.f / N_HID);
  float var = ss * (1.f / N_HID) - mu * mu;
  float r = rsqrtf(var + EPS_GN);
  float zz = (v - mu) * r * g1[h * N_HID + tid] + b1[h * N_HID + tid];
  h1[h * N_HID + tid] = fmaxf(zz, 0.f) + log1pf(expf(-fabsf(zz)));
}

// K2: blocks 0..255 -> (s,h) l2 branch: matvec + GN + softmax + atomic sum.
//     blocks 256..319 -> ws row-sums (independent work, overlapped).
__global__ __launch_bounds__(1024) void k_l2_scalar(
    const float* __restrict__ w2, const float* __restrict__ h1,
    const float* __restrict__ g2, const float* __restrict__ b2,
    const float* __restrict__ wsc, float* __restrict__ osm,
    float* __restrict__ scal) {
  int blk = blockIdx.x;
  int tid = threadIdx.x, wave = tid >> 6, lane = tid & 63;

  if (blk < 256) {
    int h = blk & 63;
    __shared__ float z_s[N_OUT];
    __shared__ float red[16];

    const float4* h1v = (const float4*)(h1 + h * N_HID);
    float4 ha = h1v[lane];        // i = 4l..4l+3
    float4 hb = h1v[64 + lane];   // i = 256+4l..
    const float* w2base = w2 + (size_t)blk * N_OUT * N_HID;
    for (int k = 0; k < 16; ++k) {
      int o = wave * 16 + k;
      const float4* row = (const float4*)(w2base + (size_t)o * N_HID);
      float4 wa = row[lane];
      float4 wb = row[64 + lane];
      float p = wa.x * ha.x + wa.y * ha.y + wa.z * ha.z + wa.w * ha.w +
                wb.x * hb.x + wb.y * hb.y + wb.z * hb.z + wb.w * hb.w;
      p = wave_sum(p);
      if (lane == 0) z_s[o] = p;
    }
    __syncthreads();

    float v = (tid < N_OUT) ? z_s[tid] : 0.f;
    float s = block_sum(v, red);
    float ss = block_sum(v * v, red);
    float mu = s * (1.f / N_OUT);
    float var = ss * (1.f / N_OUT) - mu * mu;
    float rs = rsqrtf(var + EPS_GN);
    float zn = (tid < N_OUT)
                   ? (v - mu) * rs * g2[(size_t)blk * N_OUT + tid] + b2[(size_t)blk * N_OUT + tid]
                   : -3.4e38f;
    float mx = block_max(zn, red);
    float e = (tid < N_OUT) ? expf(zn - mx) : 0.f;
    float es = block_sum(e, red);
    if (tid < N_OUT) atomicAdd(&osm[tid * N_HEADS + h], e / es);
  } else {
    int h = blk - 256;
    // 16 waves × 16 rows of 256 (one float4 per lane per row)
    for (int k = 0; k < 16; ++k) {
      int o = wave * 16 + k;
      float4 v = ((const float4*)(wsc + ((size_t)(h * N_OUT + o)) * N_OUT))[lane];
      float p = wave_sum(v.x + v.y + v.z + v.w);
      if (lane == 0) scal[o * N_HEADS + h] = p;
    }
  }
}

// K3: one block per head. last_prod (redundant per block, L2-resident),
// gate logit + sigmoid, final elementwise outputs.
__global__ __launch_bounds__(256) void k_gate_final(
    const float* __restrict__ last, const float* __restrict__ woo,
    const float* __restrict__ osm, const float* __restrict__ scal,
    float* __restrict__ out) {
  int h = blockIdx.x;
  int tid = threadIdx.x;
  __shared__ float red[4];

  // lp[o=tid] = prod_h last[o][h]  (64 contiguous floats per thread)
  const float4* row = (const float4*)(last + (size_t)tid * N_HEADS);
  float p = 1.f;
#pragma unroll
  for (int j = 0; j < 16; ++j) {
    float4 v = row[j];
    p *= v.x * v.y * v.z * v.w;
  }
  float o_sm = osm[tid * N_HEADS + h];
  float part = woo[h * 2 * N_OUT + tid] * p +
               woo[h * 2 * N_OUT + N_OUT + tid] * o_sm;
  float logit = block_sum(part, red);
  float oo = 1.f / (1.f + expf(-logit));

  float v0 = oo * o_sm;
  out[tid * N_HEADS + h] = fmaxf(v0, TINY);
  float v1 = v0 * scal[tid * N_HEADS + h];
  out[N_OUT * N_HEADS + tid * N_HEADS + h] = (fabsf(v1) <= TINY) ? TINY : v1;
}

extern "C" void kernel_launch(void* const* d_in, const int* in_sizes, int n_in,
                              void* d_out, int out_size, void* d_ws, size_t ws_size,
                              hipStream_t stream) {
  const float* x    = (const float*)d_in[0];
  const float* last = (const float*)d_in[1];
  const float* qw   = (const float*)d_in[2];
  const float* w1   = (const float*)d_in[3];
  const float* g1   = (const float*)d_in[4];
  const float* b1   = (const float*)d_in[5];
  const float* w2   = (const float*)d_in[6];
  const float* g2   = (const float*)d_in[7];
  const float* b2   = (const float*)d_in[8];
  const float* wsc  = (const float*)d_in[9];
  const float* woo  = (const float*)d_in[10];
  float* out = (float*)d_out;
  float* ws  = (float*)d_ws;

  float* h1   = ws;           // 64*512
  float* osm  = ws + 32768;   // 256*64
  float* scal = ws + 49152;   // 256*64

  hipLaunchKernelGGL(k_head1,     dim3(64),  dim3(512),  0, stream, x, qw, w1, g1, b1, h1, osm);
  hipLaunchKernelGGL(k_l2_scalar, dim3(320), dim3(1024), 0, stream, w2, h1, g2, b2, wsc, osm, scal);
  hipLaunchKernelGGL(k_gate_final,dim3(64),  dim3(256),  0, stream, last, woo, osm, scal, out);
}

// Round 3
// 262.507 us; speedup vs baseline: 1.1997x; 1.1227x over previous
//
#include <hip/hip_runtime.h>
#include <math.h>

#define N_INP 128
#define N_HID 512
#define N_OUT 256
#define N_HEADS 64
#define N_SM 4
#define EPS_GN 1e-5f
#define TINY 1e-14f

__device__ __forceinline__ float wave_sum(float v) {
#pragma unroll
  for (int off = 32; off; off >>= 1) v += __shfl_down(v, off);
  return v;
}
__device__ __forceinline__ float wave_max(float v) {
#pragma unroll
  for (int off = 32; off; off >>= 1) v = fmaxf(v, __shfl_down(v, off));
  return v;
}

// Block reductions: ALL threads must call; `red` needs blockDim/64 slots.
__device__ __forceinline__ float block_sum(float v, float* red) {
  int wave = threadIdx.x >> 6, lane = threadIdx.x & 63;
  int nw = blockDim.x >> 6;
  v = wave_sum(v);
  __syncthreads();
  if (lane == 0) red[wave] = v;
  __syncthreads();
  float s = 0.f;
  for (int i = 0; i < nw; ++i) s += red[i];
  return s;
}
__device__ __forceinline__ float block_max(float v, float* red) {
  int wave = threadIdx.x >> 6, lane = threadIdx.x & 63;
  int nw = blockDim.x >> 6;
  v = wave_max(v);
  __syncthreads();
  if (lane == 0) red[wave] = v;
  __syncthreads();
  float s = -3.4e38f;
  for (int i = 0; i < nw; ++i) s = fmaxf(s, red[i]);
  return s;
}

// K1: 256 blocks = (head h, quarter oq). Redundant sub compute (x L2-hot),
// 128 raw z1 rows per block. Also zeroes osm (64 elems per block).
__global__ __launch_bounds__(512) void k_z1(
    const float* __restrict__ x, const float* __restrict__ qw,
    const float* __restrict__ w1, float* __restrict__ z1,
    float* __restrict__ osm) {
  int blk = blockIdx.x;            // h*4 + oq
  int h = blk >> 2, oq = blk & 3;
  int tid = threadIdx.x, wave = tid >> 6, lane = tid & 63;
  __shared__ float sub_s[N_INP];

  if (tid < 64) osm[blk * 64 + tid] = 0.f;

  // sub[r] = x[r]·qw[h]; 8 waves × 16 rows
  float2 qv = ((const float2*)(qw + h * N_INP))[lane];
  for (int r = wave; r < N_INP; r += 8) {
    float2 xv = ((const float2*)(x + r * N_INP))[lane];
    float p = wave_sum(xv.x * qv.x + xv.y * qv.y);
    if (lane == 0) sub_s[r] = p;
  }
  __syncthreads();

  // z1 rows [oq*128, oq*128+128): 8 waves × 16 rows
  float2 sv = ((const float2*)sub_s)[lane];
  const float* w1h = w1 + ((size_t)h * N_HID + (size_t)oq * 128) * N_INP;
  for (int k = 0; k < 16; ++k) {
    int o = wave * 16 + k;  // 0..127
    float2 wv = ((const float2*)(w1h + (size_t)o * N_INP))[lane];
    float p = wave_sum(wv.x * sv.x + wv.y * sv.y);
    if (lane == 0) z1[h * N_HID + oq * 128 + o] = p;
  }
}

// K2: 256 blocks = one per (s,h). GN1+softplus from z1 (redundant x4 per head,
// deterministic), then the 512KB w2 stream + GN2 + softmax + atomic sum,
// plus this block's 64 ws rows (64KB) fused in. Every block: identical 576KB.
__global__ __launch_bounds__(1024) void k_l2_scalar(
    const float* __restrict__ z1, const float* __restrict__ g1,
    const float* __restrict__ b1, const float* __restrict__ w2,
    const float* __restrict__ g2, const float* __restrict__ b2,
    const float* __restrict__ wsc, float* __restrict__ osm,
    float* __restrict__ scal) {
  int blk = blockIdx.x;            // s*64 + h
  int s = blk >> 6, h = blk & 63;
  int tid = threadIdx.x, wave = tid >> 6, lane = tid & 63;
  __shared__ float h1_s[N_HID];
  __shared__ float z_s[N_OUT];
  __shared__ float red[16];

  // GN1 over 512 + softplus -> h1_s (LDS)
  float v1 = (tid < N_HID) ? z1[h * N_HID + tid] : 0.f;
  float s1 = block_sum(v1, red);
  float ss1 = block_sum(v1 * v1, red);
  float mu1 = s1 * (1.f / N_HID);
  float var1 = ss1 * (1.f / N_HID) - mu1 * mu1;
  float r1 = rsqrtf(var1 + EPS_GN);
  if (tid < N_HID) {
    float zz = (v1 - mu1) * r1 * g1[h * N_HID + tid] + b1[h * N_HID + tid];
    h1_s[tid] = fmaxf(zz, 0.f) + log1pf(expf(-fabsf(zz)));
  }
  __syncthreads();

  // per-lane o-invariant h1 fragment in registers
  float4 ha = ((const float4*)h1_s)[lane];        // i = 4l..4l+3
  float4 hb = ((const float4*)h1_s)[64 + lane];   // i = 256+4l..

  // fused ws slice: rows o in [s*64, (s+1)*64), 16 waves × 4 rows
  for (int k = 0; k < 4; ++k) {
    int o = s * 64 + wave * 4 + k;
    float4 v = ((const float4*)(wsc + ((size_t)(h * N_OUT + o)) * N_OUT))[lane];
    float p = wave_sum(v.x + v.y + v.z + v.w);
    if (lane == 0) scal[o * N_HEADS + h] = p;
  }

  // main stream: z[o] = w2[s][h][o]·h1
  const float* w2base = w2 + (size_t)blk * N_OUT * N_HID;
  for (int k = 0; k < 16; ++k) {
    int o = wave * 16 + k;
    const float4* row = (const float4*)(w2base + (size_t)o * N_HID);
    float4 wa = row[lane];
    float4 wb = row[64 + lane];
    float p = wa.x * ha.x + wa.y * ha.y + wa.z * ha.z + wa.w * ha.w +
              wb.x * hb.x + wb.y * hb.y + wb.z * hb.z + wb.w * hb.w;
    p = wave_sum(p);
    if (lane == 0) z_s[o] = p;
  }
  __syncthreads();

  // GN2 over 256 + softmax + atomic accumulate over s
  float v = (tid < N_OUT) ? z_s[tid] : 0.f;
  float sz = block_sum(v, red);
  float ssz = block_sum(v * v, red);
  float mu = sz * (1.f / N_OUT);
  float var = ssz * (1.f / N_OUT) - mu * mu;
  float rs = rsqrtf(var + EPS_GN);
  float zn = (tid < N_OUT)
                 ? (v - mu) * rs * g2[(size_t)blk * N_OUT + tid] + b2[(size_t)blk * N_OUT + tid]
                 : -3.4e38f;
  float mx = block_max(zn, red);
  float e = (tid < N_OUT) ? expf(zn - mx) : 0.f;
  float es = block_sum(e, red);
  if (tid < N_OUT) atomicAdd(&osm[tid * N_HEADS + h], e / es);
}

// K3: one block per head. last_prod (redundant per block, L2-resident),
// gate logit + sigmoid, final elementwise outputs.
__global__ __launch_bounds__(256) void k_gate_final(
    const float* __restrict__ last, const float* __restrict__ woo,
    const float* __restrict__ osm, const float* __restrict__ scal,
    float* __restrict__ out) {
  int h = blockIdx.x;
  int tid = threadIdx.x;
  __shared__ float red[4];

  // lp[o=tid] = prod_h last[o][h]  (64 contiguous floats per thread)
  const float4* row = (const float4*)(last + (size_t)tid * N_HEADS);
  float p = 1.f;
#pragma unroll
  for (int j = 0; j < 16; ++j) {
    float4 v = row[j];
    p *= v.x * v.y * v.z * v.w;
  }
  float o_sm = osm[tid * N_HEADS + h];
  float part = woo[h * 2 * N_OUT + tid] * p +
               woo[h * 2 * N_OUT + N_OUT + tid] * o_sm;
  float logit = block_sum(part, red);
  float oo = 1.f / (1.f + expf(-logit));

  float v0 = oo * o_sm;
  out[tid * N_HEADS + h] = fmaxf(v0, TINY);
  float v1 = v0 * scal[tid * N_HEADS + h];
  out[N_OUT * N_HEADS + tid * N_HEADS + h] = (fabsf(v1) <= TINY) ? TINY : v1;
}

extern "C" void kernel_launch(void* const* d_in, const int* in_sizes, int n_in,
                              void* d_out, int out_size, void* d_ws, size_t ws_size,
                              hipStream_t stream) {
  const float* x    = (const float*)d_in[0];
  const float* last = (const float*)d_in[1];
  const float* qw   = (const float*)d_in[2];
  const float* w1   = (const float*)d_in[3];
  const float* g1   = (const float*)d_in[4];
  const float* b1   = (const float*)d_in[5];
  const float* w2   = (const float*)d_in[6];
  const float* g2   = (const float*)d_in[7];
  const float* b2   = (const float*)d_in[8];
  const float* wsc  = (const float*)d_in[9];
  const float* woo  = (const float*)d_in[10];
  float* out = (float*)d_out;
  float* ws  = (float*)d_ws;

  float* z1   = ws;           // 64*512
  float* osm  = ws + 32768;   // 256*64
  float* scal = ws + 49152;   // 256*64

  hipLaunchKernelGGL(k_z1,        dim3(256), dim3(512),  0, stream, x, qw, w1, z1, osm);
  hipLaunchKernelGGL(k_l2_scalar, dim3(256), dim3(1024), 0, stream, z1, g1, b1, w2, g2, b2, wsc, osm, scal);
  hipLaunchKernelGGL(k_gate_final,dim3(64),  dim3(256),  0, stream, last, woo, osm, scal, out);
}